// Round 12
// baseline (44.100 us; speedup 1.0000x reference)
//
#include <hip/hip_runtime.h>

// DirectionalScan: B=4, H=64, W=64, D=512, N=8
// out = ((scan_h(x) + scan_v(x)) @ Wp^T) + b_proj
#define BB 4
#define HH 64
#define WW 64
#define DD 512
#define NS 8
#define MROWS (BB * HH * WW)  // 16384

typedef __attribute__((ext_vector_type(8))) __bf16 bf16x8;
typedef __attribute__((ext_vector_type(4))) float f32x4;

__device__ inline short f2bf(float f) {  // RNE f32 -> bf16 bits
  unsigned u = __float_as_uint(f);
  return (short)((u + 0x7fff + ((u >> 16) & 1)) >> 16);
}
__device__ inline float bf2f(short s) {
  return __uint_as_float(((unsigned)(unsigned short)s) << 16);
}

// one SSM step: update states s[], return C.s + D*x via 3-level tree
__device__ inline float ssm_step(float xv, float* s, const float* a,
                                 const float* bm, const float* cm, float dk) {
#pragma unroll
  for (int n = 0; n < NS; ++n) s[n] = fmaf(a[n], s[n], bm[n] * xv);
  float p0 = s[0] * cm[0], p1 = s[1] * cm[1], p2 = s[2] * cm[2],
        p3 = s[3] * cm[3], p4 = s[4] * cm[4], p5 = s[5] * cm[5],
        p6 = s[6] * cm[6], p7 = s[7] * cm[7];
  float q0 = p0 + p1, q1 = p2 + p3, q2 = p4 + p5, q3 = p6 + p7;
  return fmaf(dk, xv, (q0 + q1) + (q2 + q3));
}

// ---------------- kernel 1: scan_h (writes y_h bf16) + fused Wp->bf16 -------
__global__ __launch_bounds__(256) void scan_h_kernel(
    const float* __restrict__ x, const float* __restrict__ A,
    const float* __restrict__ Bm, const float* __restrict__ Cm,
    const float* __restrict__ Dsk, short* __restrict__ y,
    const float* __restrict__ Wp, short* __restrict__ wb) {
  if (blockIdx.x >= 256) {
    const int cid = (blockIdx.x - 256) * 2 + blockIdx.y;  // 0..127
    const int i = (cid * 256 + (int)threadIdx.x) * 8;
    const float4 v0 = *(const float4*)&Wp[i];
    const float4 v1 = *(const float4*)&Wp[i + 4];
    short r[8];
    r[0] = f2bf(v0.x); r[1] = f2bf(v0.y); r[2] = f2bf(v0.z); r[3] = f2bf(v0.w);
    r[4] = f2bf(v1.x); r[5] = f2bf(v1.y); r[6] = f2bf(v1.z); r[7] = f2bf(v1.w);
    *(short4*)&wb[i] = *(short4*)&r[0];
    *(short4*)&wb[i + 4] = *(short4*)&r[4];
    return;
  }

  const int seq = blockIdx.x;  // 0..255 = b*64 + w
  const int d = blockIdx.y * 256 + threadIdx.x;
  const int b = seq >> 6;
  const int r = seq & 63;

  size_t base = ((size_t)b * HH * WW + r) * DD + d;
  const size_t step = (size_t)WW * DD;

  float a[NS], bm[NS], cm[NS], s[NS];
#pragma unroll
  for (int i = 0; i < NS; i += 4) {
    float4 t;
    t = *(const float4*)&A[(size_t)d * NS + i];
    a[i] = t.x; a[i + 1] = t.y; a[i + 2] = t.z; a[i + 3] = t.w;
    t = *(const float4*)&Bm[(size_t)d * NS + i];
    bm[i] = t.x; bm[i + 1] = t.y; bm[i + 2] = t.z; bm[i + 3] = t.w;
    t = *(const float4*)&Cm[(size_t)d * NS + i];
    cm[i] = t.x; cm[i + 1] = t.y; cm[i + 2] = t.z; cm[i + 3] = t.w;
  }
  const float dk = Dsk[d];
#pragma unroll
  for (int i = 0; i < NS; ++i) s[i] = 0.f;

  // 2-chunk-ahead prefetch (4-slot ring, unroll 4 keeps indices static)
  float xs[4][8];
#pragma unroll
  for (int i = 0; i < 8; ++i) xs[0][i] = x[base + (size_t)i * step];
#pragma unroll
  for (int i = 0; i < 8; ++i) xs[1][i] = x[base + (size_t)(8 + i) * step];

#pragma unroll 4
  for (int c = 0; c < 8; ++c) {
    const int cur = c & 3;
    if (c < 6) {
      const size_t pbase = base + 16 * step;
#pragma unroll
      for (int i = 0; i < 8; ++i)
        xs[(c + 2) & 3][i] = x[pbase + (size_t)i * step];
    }
#pragma unroll
    for (int i = 0; i < 8; ++i)
      y[base + (size_t)i * step] = f2bf(ssm_step(xs[cur][i], s, a, bm, cm, dk));
    base += 8 * step;
  }
}

// ------- kernel 2: split-scan_v + y_h add + GEMM + bias --------------------
// 1024 threads (16 waves) per (b,h) block.
// Group A (waves 0-7) scans w=0..31; group B (waves 8-15) scans w=32..63
// from zero state, concurrently. A's final states -> sA LDS; B then applies
// the superposition fix-up y += sum_n cm*a^(w-31)*sA (bf16 RMW in Ys).
// GEMM: 16 waves x 32 cols, wave-private Bs staging, counted vmcnt.
__global__ __launch_bounds__(1024) void scanv_gemm_kernel(
    const float* __restrict__ x, const float* __restrict__ A,
    const float* __restrict__ Bm, const float* __restrict__ Cm,
    const float* __restrict__ Dsk, const short* __restrict__ yh,
    const short* __restrict__ Wb, const float* __restrict__ bias,
    float* __restrict__ out) {
  __shared__ __align__(16) char LDSBUF[131072];  // 128 KB
  short* Ys = (short*)LDSBUF;                    // 64 KB [w][d^((w&7)<<3)]
  short* Bs0 = (short*)(LDSBUF + 65536);         // 32 KB [n][k^((n&3)<<3)]
  short* Bs1 = (short*)(LDSBUF + 98304);         // 32 KB
  float* sA = (float*)(LDSBUF + 98304);          // 16 KB alias (dead pre-GEMM)

  const int tid = (int)threadIdx.x;  // 0..1023
  const int lane = tid & 63;
  const int wid = tid >> 6;   // 0..15
  const int grp = tid >> 9;   // 0: w 0..31, 1: w 32..63
  const int d = tid & 511;
  const int m0 = blockIdx.x * 64;

  // stage Bs K-slab ks (32 wide). Wave wid writes chunks wid*2, wid*2+1 =
  // rows wid*32..wid*32+31 — exactly the rows it later reads (wave-private).
  auto stageB = [&](int ks, short* bsb) {
    const int k0 = ks * 32;
#pragma unroll
    for (int c = 0; c < 2; ++c) {
      const int chunk = wid * 2 + c;           // 0..31, 16 rows each
      const int n = chunk * 16 + (lane >> 2);  // Wp row
      const int kslot = ((lane & 3) ^ (n & 3)) << 3;
      const short* g = &Wb[(size_t)n * DD + k0 + kslot];
      __builtin_amdgcn_global_load_lds(
          (const __attribute__((address_space(1))) unsigned int*)g,
          (__attribute__((address_space(3))) unsigned int*)((char*)bsb +
                                                            chunk * 1024),
          16, 0, 0);
    }
  };

  float a[NS], bm[NS], cm[NS], s[NS];
#pragma unroll
  for (int i = 0; i < NS; i += 4) {
    float4 t;
    t = *(const float4*)&A[(size_t)d * NS + i];
    a[i] = t.x; a[i + 1] = t.y; a[i + 2] = t.z; a[i + 3] = t.w;
    t = *(const float4*)&Bm[(size_t)d * NS + i];
    bm[i] = t.x; bm[i + 1] = t.y; bm[i + 2] = t.z; bm[i + 3] = t.w;
    t = *(const float4*)&Cm[(size_t)d * NS + i];
    cm[i] = t.x; cm[i + 1] = t.y; cm[i + 2] = t.z; cm[i + 3] = t.w;
  }
  const float dk = Dsk[d];
#pragma unroll
  for (int i = 0; i < NS; ++i) s[i] = 0.f;

  stageB(0, Bs0);  // lands under the scan; long done before GEMM

  // ---- phase 1: both groups scan their 32 w's (local state from 0) ----
  size_t base = (size_t)m0 * DD + (size_t)(grp * 32) * DD + d;
  float xs[2][8], yp[2][8];
#pragma unroll
  for (int i = 0; i < 8; ++i) xs[0][i] = x[base + (size_t)i * DD];
#pragma unroll
  for (int i = 0; i < 8; ++i) yp[0][i] = bf2f(yh[base + (size_t)i * DD]);

#pragma unroll 2
  for (int c = 0; c < 4; ++c) {
    const int cur = c & 1, nxt = cur ^ 1;
    const size_t nbase = base + 8 * DD;
    if (c < 3) {
#pragma unroll
      for (int i = 0; i < 8; ++i) xs[nxt][i] = x[nbase + (size_t)i * DD];
#pragma unroll
      for (int i = 0; i < 8; ++i) yp[nxt][i] = bf2f(yh[nbase + (size_t)i * DD]);
    }
#pragma unroll
    for (int i = 0; i < 8; ++i) {
      const int w = grp * 32 + c * 8 + i;
      const float acc = ssm_step(xs[cur][i], s, a, bm, cm, dk) + yp[cur][i];
      Ys[w * DD + (d ^ ((w & 7) << 3))] = f2bf(acc);
    }
    base = nbase;
  }

  // A publishes its final states (SoA: conflict-free scalar access)
  if (grp == 0) {
#pragma unroll
    for (int n = 0; n < NS; ++n) sA[n * 512 + d] = s[n];
  }
  __syncthreads();

  // ---- phase 2: B applies superposition fix-up to its 32 rows ----
  if (grp == 1) {
    float ap[NS], sv[NS];
#pragma unroll
    for (int n = 0; n < NS; ++n) {
      sv[n] = sA[n * 512 + d];
      ap[n] = a[n];  // a^(w-31) for w=32
    }
#pragma unroll 4
    for (int w = 32; w < 64; ++w) {
      float p0 = (cm[0] * ap[0]) * sv[0], p1 = (cm[1] * ap[1]) * sv[1],
            p2 = (cm[2] * ap[2]) * sv[2], p3 = (cm[3] * ap[3]) * sv[3],
            p4 = (cm[4] * ap[4]) * sv[4], p5 = (cm[5] * ap[5]) * sv[5],
            p6 = (cm[6] * ap[6]) * sv[6], p7 = (cm[7] * ap[7]) * sv[7];
      const float corr = ((p0 + p1) + (p2 + p3)) + ((p4 + p5) + (p6 + p7));
      const int idx = w * DD + (d ^ ((w & 7) << 3));
      Ys[idx] = f2bf(bf2f(Ys[idx]) + corr);
#pragma unroll
      for (int n = 0; n < NS; ++n) ap[n] *= a[n];
    }
  }
  __syncthreads();  // Ys fully corrected; sA dead (Bs1 reusable)

  // ---- GEMM: out[m0..+63][0..511] = Ys @ Wb^T + bias (16 waves) ----
  f32x4 acc4[4][2];
#pragma unroll
  for (int m = 0; m < 4; ++m)
#pragma unroll
    for (int n = 0; n < 2; ++n) acc4[m][n] = (f32x4){0.f, 0.f, 0.f, 0.f};

  const int fr = lane & 15;
  const int kfr = (lane >> 4) * 8;  // 0,8,16,24
  const int nc0 = wid * 32;         // this wave's 32 out columns

  int cur = 0;
  for (int ks = 0; ks < 16; ++ks) {  // K-steps of 32, double-buffered
    if (ks < 15) {
      stageB(ks + 1, (cur ^ 1) ? Bs1 : Bs0);
      asm volatile("s_waitcnt vmcnt(2)" ::: "memory");  // stage(ks) done
    } else {
      asm volatile("s_waitcnt vmcnt(0)" ::: "memory");
    }
    __builtin_amdgcn_sched_barrier(0);  // rule #18: fence ds_reads below wait

    const short* bsr = cur ? Bs1 : Bs0;
    bf16x8 af[4], bfv[2];
    const int kg = ks * 32 + kfr;
#pragma unroll
    for (int m = 0; m < 4; ++m) {
      const int r = m * 16 + fr;  // Y row 0..63
      af[m] = *(const bf16x8*)(const void*)&Ys[r * DD + (kg ^ ((r & 7) << 3))];
    }
#pragma unroll
    for (int n = 0; n < 2; ++n) {
      const int nn = nc0 + n * 16 + fr;  // out col (wave-private rows)
      bfv[n] = *(const bf16x8*)(const void*)&bsr[nn * 32 +
                                                 (kfr ^ ((nn & 3) << 3))];
    }
#pragma unroll
    for (int m = 0; m < 4; ++m)
#pragma unroll
      for (int n = 0; n < 2; ++n)
        acc4[m][n] = __builtin_amdgcn_mfma_f32_16x16x32_bf16(
            af[m], bfv[n], acc4[m][n], 0, 0, 0);
    __builtin_amdgcn_sched_barrier(0);  // keep iter body intact (WAR safety)
    cur ^= 1;
  }

  // epilogue: D layout col=lane&15, row=(lane>>4)*4+j  [m89 verified]
  const int c16 = lane & 15;
  const int r4 = (lane >> 4) * 4;
  float bv[2];
#pragma unroll
  for (int n = 0; n < 2; ++n) bv[n] = bias[nc0 + n * 16 + c16];
#pragma unroll
  for (int m = 0; m < 4; ++m) {
    const int rowb = m0 + m * 16 + r4;
#pragma unroll
    for (int n = 0; n < 2; ++n) {
      const int col = nc0 + n * 16 + c16;
#pragma unroll
      for (int j = 0; j < 4; ++j)
        out[(size_t)(rowb + j) * DD + col] = acc4[m][n][j] + bv[n];
    }
  }
}

// ---------------- launcher ----------------
extern "C" void kernel_launch(void* const* d_in, const int* in_sizes, int n_in,
                              void* d_out, int out_size, void* d_ws,
                              size_t ws_size, hipStream_t stream) {
  const float* x = (const float*)d_in[0];
  const float* A = (const float*)d_in[3];
  const float* Bm = (const float*)d_in[4];
  const float* Cm = (const float*)d_in[5];
  const float* Dsk = (const float*)d_in[6];
  const float* Wp = (const float*)d_in[7];
  const float* bpj = (const float*)d_in[8];
  float* out = (float*)d_out;

  short* yh = (short*)d_ws;                                    // 16 MB bf16 y_h
  short* wb = (short*)((char*)d_ws + (size_t)MROWS * DD * 2);  // 512 KB bf16 Wp

  const dim3 grid_h(256 + 64, DD / 256);
  scan_h_kernel<<<grid_h, 256, 0, stream>>>(x, A, Bm, Cm, Dsk, yh, Wp, wb);

  scanv_gemm_kernel<<<BB * HH, 1024, 0, stream>>>(x, A, Bm, Cm, Dsk, yh, wb,
                                                  bpj, out);
}